// Round 3
// baseline (1442.167 us; speedup 1.0000x reference)
//
#include <hip/hip_runtime.h>
#include <hip/hip_bf16.h>

#define D_MODEL 1024
#define D_STATE 16
#define D_CONV  4
#define D_INNER 2048
#define DT_RANK 64
#define B_SZ 2
#define SEQ 1024
#define MR (B_SZ*SEQ)   // 2048 rows total

__device__ __forceinline__ float ldf(const __hip_bfloat16* p) { return __bfloat162float(*p); }
__device__ __forceinline__ float ldf(const float* p) { return *p; }

// C[M,N] = A[M,K] @ B[K,N].  A: row-major (dtype AT), B: fp32 row-major.
// EPI 0: store float; EPI 1: store float softplus(acc + bias[n]); EPI 2: store bf16.
template <typename AT, int EPI>
__global__ __launch_bounds__(256) void gemm_kernel(
    const AT* __restrict__ A, int lda,
    const float* __restrict__ B, int ldb,
    const float* __restrict__ bias,
    void* __restrict__ C, int ldc,
    int M, int N, int K)
{
  __shared__ float As[16][64];
  __shared__ float Bs[16][64];
  const int tid = threadIdx.x;
  const int tx = tid & 15, ty = tid >> 4;
  const int m0 = blockIdx.y * 64, n0 = blockIdx.x * 64;
  float acc[4][4] = {};
  const int la_m = tid >> 2, la_k = (tid & 3) * 4;   // A-tile: 64 rows x 16 k
  const int lb_k = tid >> 4, lb_n = (tid & 15) * 4;  // B-tile: 16 k x 64 cols

  for (int k0 = 0; k0 < K; k0 += 16) {
#pragma unroll
    for (int i = 0; i < 4; ++i)
      As[la_k + i][la_m] = ldf(&A[(size_t)(m0 + la_m) * lda + (k0 + la_k + i)]);
#pragma unroll
    for (int i = 0; i < 4; ++i) {
      int n = n0 + lb_n + i;
      Bs[lb_k][lb_n + i] = (n < N) ? B[(size_t)(k0 + lb_k) * ldb + n] : 0.f;
    }
    __syncthreads();
#pragma unroll
    for (int kk = 0; kk < 16; ++kk) {
      float a[4], b[4];
#pragma unroll
      for (int i = 0; i < 4; ++i) a[i] = As[kk][ty * 4 + i];
#pragma unroll
      for (int j = 0; j < 4; ++j) b[j] = Bs[kk][tx * 4 + j];
#pragma unroll
      for (int i = 0; i < 4; ++i)
#pragma unroll
        for (int j = 0; j < 4; ++j)
          acc[i][j] += a[i] * b[j];
    }
    __syncthreads();
  }

#pragma unroll
  for (int i = 0; i < 4; ++i) {
    int m = m0 + ty * 4 + i;
#pragma unroll
    for (int j = 0; j < 4; ++j) {
      int n = n0 + tx * 4 + j;
      if (n >= N) continue;
      float v = acc[i][j];
      if (EPI == 0) {
        ((float*)C)[(size_t)m * ldc + n] = v;
      } else if (EPI == 1) {
        float xv = v + bias[n];
        ((float*)C)[(size_t)m * ldc + n] = (xv > 15.f) ? xv : log1pf(__expf(xv));
      } else {
        ((__hip_bfloat16*)C)[(size_t)m * ldc + n] = __float2bfloat16(v);
      }
    }
  }
}

// Depthwise causal conv over SEQ (4 taps) + bias + SiLU.
// x_e = xz[:, 0:2048] (bf16); writes xc (fp32, [MR, 2048]).
__global__ __launch_bounds__(256) void conv_silu_kernel(
    const __hip_bfloat16* __restrict__ xz,
    const float* __restrict__ cw,
    const float* __restrict__ cb,
    float* __restrict__ xc)
{
  int idx = blockIdx.x * 256 + threadIdx.x;     // over MR*D_INNER
  int c = idx & (D_INNER - 1);
  int row = idx >> 11;                          // b*SEQ + l
  int l = row & (SEQ - 1);
  int b = row >> 10;
  float acc = cb[c];
#pragma unroll
  for (int k = 0; k < D_CONV; ++k) {
    int ll = l - (D_CONV - 1) + k;
    if (ll >= 0)
      acc += __bfloat162float(xz[((size_t)(b * SEQ + ll)) * (2 * D_INNER) + c]) *
             cw[c * D_CONV + k];
  }
  xc[idx] = acc / (1.f + __expf(-acc));         // silu
}

// Sequential SSM scan. One 16-lane group per (b,d) chain; lane = state n.
// yg aliases delta (in-place): delta[row,d] is read only by this chain at
// l==row, before lane 0 writes the same element (same-wave lockstep).
__global__ __launch_bounds__(256) void scan_kernel(
    const float* __restrict__ delta,   // [MR, 2048]
    const float* __restrict__ xc,      // [MR, 2048]
    const float* __restrict__ xdbl,    // [MR, 96]  (B at +64, C at +80)
    const __hip_bfloat16* __restrict__ xz,   // [MR, 4096] bf16 (z at +2048)
    const float* __restrict__ A_log,   // [2048,16]
    const float* __restrict__ Dp,      // [2048]
    float* __restrict__ yg)            // [MR, 2048]  y * silu(z)  (== delta)
{
  const int tid = threadIdx.x;
  const int n = tid & 15;
  const int grp = tid >> 4;
  const int chain = blockIdx.x * 16 + grp;   // 0..4095
  const int b = chain >> 11;
  const int d = chain & (D_INNER - 1);
  const float a_c = -__expf(A_log[d * D_STATE + n]);
  const float Dv = Dp[d];
  float h = 0.f;
  const int base = b * SEQ;
  for (int l = 0; l < SEQ; ++l) {
    const size_t row = base + l;
    float dv  = delta[row * D_INNER + d];
    float xcv = xc[row * D_INNER + d];
    float Bv  = xdbl[row * 96 + DT_RANK + n];
    float Cv  = xdbl[row * 96 + DT_RANK + D_STATE + n];
    h = __expf(dv * a_c) * h + dv * Bv * xcv;
    float contrib = h * Cv;
#pragma unroll
    for (int off = 8; off; off >>= 1) contrib += __shfl_xor(contrib, off, 16);
    if (n == 0) {
      float zv = __bfloat162float(xz[row * (2 * D_INNER) + D_INNER + d]);
      float yv = contrib + xcv * Dv;
      yg[row * D_INNER + d] = yv * (zv / (1.f + __expf(-zv)));
    }
  }
}

extern "C" void kernel_launch(void* const* d_in, const int* in_sizes, int n_in,
                              void* d_out, int out_size, void* d_ws, size_t ws_size,
                              hipStream_t stream)
{
  // Reference dtypes: ALL inputs and the output are float32.
  const float* x     = (const float*)d_in[0];
  const float* W_in  = (const float*)d_in[1];
  const float* cw    = (const float*)d_in[2];
  const float* cb    = (const float*)d_in[3];
  const float* W_x   = (const float*)d_in[4];
  const float* W_dt  = (const float*)d_in[5];
  const float* b_dt  = (const float*)d_in[6];
  const float* A_log = (const float*)d_in[7];
  const float* Dp    = (const float*)d_in[8];
  const float* W_out = (const float*)d_in[9];
  float* out = (float*)d_out;

  // Workspace layout (51.2 MB total):
  //   xz   bf16 [MR,4096]  = 16.8 MB  (quantized intermediate; threshold is 2%)
  //   xc   f32  [MR,2048]  = 16.8 MB
  //   xdbl f32  [MR,  96]  =  0.8 MB
  //   delta f32 [MR,2048]  = 16.8 MB   (yg aliases delta — safe, see scan_kernel)
  char* wsb = (char*)d_ws;
  __hip_bfloat16* xz = (__hip_bfloat16*)wsb;
  float* xc    = (float*)(wsb + (size_t)MR * 4096 * 2);
  float* xdbl  = xc + (size_t)MR * 2048;
  float* delta = xdbl + (size_t)MR * 96;
  float* yg    = delta;   // in-place

  dim3 blk(256);

  // 1. xz = x @ W_in   (M=2048, N=4096, K=1024), bf16 store
  gemm_kernel<float, 2><<<dim3(4096 / 64, MR / 64), blk, 0, stream>>>(
      x, D_MODEL, W_in, 2 * D_INNER, nullptr, xz, 2 * D_INNER, MR, 2 * D_INNER, D_MODEL);

  // 2. conv + silu -> xc
  conv_silu_kernel<<<(MR * D_INNER) / 256, blk, 0, stream>>>(xz, cw, cb, xc);

  // 3. xdbl = xc @ W_x   (M=2048, N=96, K=2048)
  gemm_kernel<float, 0><<<dim3(2, MR / 64), blk, 0, stream>>>(
      xc, D_INNER, W_x, 96, nullptr, xdbl, 96, MR, 96, D_INNER);

  // 4. delta = softplus(xdbl[:, :64] @ W_dt + b_dt)   (M=2048, N=2048, K=64)
  gemm_kernel<float, 1><<<dim3(D_INNER / 64, MR / 64), blk, 0, stream>>>(
      xdbl, 96, W_dt, D_INNER, b_dt, delta, D_INNER, MR, D_INNER, DT_RANK);

  // 5. SSM scan + D skip + silu(z) gating -> yg (in-place over delta)
  scan_kernel<<<(B_SZ * D_INNER) / 16, blk, 0, stream>>>(delta, xc, xdbl, xz, A_log, Dp, yg);

  // 6. out = yg @ W_out   (M=2048, N=1024, K=2048), fp32 store
  gemm_kernel<float, 0><<<dim3(D_MODEL / 64, MR / 64), blk, 0, stream>>>(
      yg, D_INNER, W_out, D_MODEL, nullptr, out, D_MODEL, MR, D_MODEL, D_INNER);
}

// Round 4
// 951.165 us; speedup vs baseline: 1.5162x; 1.5162x over previous
//
#include <hip/hip_runtime.h>
#include <hip/hip_bf16.h>

#define D_MODEL 1024
#define D_STATE 16
#define D_CONV  4
#define D_INNER 2048
#define DT_RANK 64
#define B_SZ 2
#define SEQ 1024
#define MR (B_SZ*SEQ)   // 2048 rows total

__device__ __forceinline__ float ldf(const __hip_bfloat16* p) { return __bfloat162float(*p); }
__device__ __forceinline__ float ldf(const float* p) { return *p; }

// C[M,N] = A[M,K] @ B[K,N].  A: row-major (dtype AT), B: fp32 row-major.
// EPI 0: store float; EPI 1: store float softplus(acc + bias[n]); EPI 2: store bf16.
template <typename AT, int EPI>
__global__ __launch_bounds__(256) void gemm_kernel(
    const AT* __restrict__ A, int lda,
    const float* __restrict__ B, int ldb,
    const float* __restrict__ bias,
    void* __restrict__ C, int ldc,
    int M, int N, int K)
{
  __shared__ float As[16][64];
  __shared__ float Bs[16][64];
  const int tid = threadIdx.x;
  const int tx = tid & 15, ty = tid >> 4;
  const int m0 = blockIdx.y * 64, n0 = blockIdx.x * 64;
  float acc[4][4] = {};
  const int la_m = tid >> 2, la_k = (tid & 3) * 4;   // A-tile: 64 rows x 16 k
  const int lb_k = tid >> 4, lb_n = (tid & 15) * 4;  // B-tile: 16 k x 64 cols

  for (int k0 = 0; k0 < K; k0 += 16) {
#pragma unroll
    for (int i = 0; i < 4; ++i)
      As[la_k + i][la_m] = ldf(&A[(size_t)(m0 + la_m) * lda + (k0 + la_k + i)]);
#pragma unroll
    for (int i = 0; i < 4; ++i) {
      int n = n0 + lb_n + i;
      Bs[lb_k][lb_n + i] = (n < N) ? B[(size_t)(k0 + lb_k) * ldb + n] : 0.f;
    }
    __syncthreads();
#pragma unroll
    for (int kk = 0; kk < 16; ++kk) {
      float a[4], b[4];
#pragma unroll
      for (int i = 0; i < 4; ++i) a[i] = As[kk][ty * 4 + i];
#pragma unroll
      for (int j = 0; j < 4; ++j) b[j] = Bs[kk][tx * 4 + j];
#pragma unroll
      for (int i = 0; i < 4; ++i)
#pragma unroll
        for (int j = 0; j < 4; ++j)
          acc[i][j] += a[i] * b[j];
    }
    __syncthreads();
  }

#pragma unroll
  for (int i = 0; i < 4; ++i) {
    int m = m0 + ty * 4 + i;
#pragma unroll
    for (int j = 0; j < 4; ++j) {
      int n = n0 + tx * 4 + j;
      if (n >= N) continue;
      float v = acc[i][j];
      if (EPI == 0) {
        ((float*)C)[(size_t)m * ldc + n] = v;
      } else if (EPI == 1) {
        float xv = v + bias[n];
        ((float*)C)[(size_t)m * ldc + n] = (xv > 15.f) ? xv : log1pf(__expf(xv));
      } else {
        ((__hip_bfloat16*)C)[(size_t)m * ldc + n] = __float2bfloat16(v);
      }
    }
  }
}

// Depthwise causal conv over SEQ (4 taps) + bias + SiLU.
// x_e = xz[:, 0:2048] (bf16); writes xc (fp32, [MR, 2048]).
__global__ __launch_bounds__(256) void conv_silu_kernel(
    const __hip_bfloat16* __restrict__ xz,
    const float* __restrict__ cw,
    const float* __restrict__ cb,
    float* __restrict__ xc)
{
  int idx = blockIdx.x * 256 + threadIdx.x;     // over MR*D_INNER
  int c = idx & (D_INNER - 1);
  int row = idx >> 11;                          // b*SEQ + l
  int l = row & (SEQ - 1);
  int b = row >> 10;
  float acc = cb[c];
#pragma unroll
  for (int k = 0; k < D_CONV; ++k) {
    int ll = l - (D_CONV - 1) + k;
    if (ll >= 0)
      acc += __bfloat162float(xz[((size_t)(b * SEQ + ll)) * (2 * D_INNER) + c]) *
             cw[c * D_CONV + k];
  }
  xc[idx] = acc / (1.f + __expf(-acc));         // silu
}

// Chunked parallel SSM scan. One block per (b,d) chain; thread = (n, seg):
// n = tid&15 (state index), seg = tid>>4 (16 segments x 64 timesteps).
// Pass 1: compose each segment's 64-step affine map into (aprod, bacc).
// LDS: 16-step exclusive inter-segment scan per n.
// Pass 2: rescan with segment-entry state, contract with C across n (shfl),
// gate with silu(z), store. yg aliases delta: each row is read only by its
// own 16-lane group in the same iteration before lane 0 overwrites it, and
// all pass-1 reads complete before the barrier.
__global__ __launch_bounds__(256) void scan_kernel(
    const float* __restrict__ delta,   // [MR, 2048]
    const float* __restrict__ xc,      // [MR, 2048]
    const float* __restrict__ xdbl,    // [MR, 96]  (B at +64, C at +80)
    const __hip_bfloat16* __restrict__ xz,   // [MR, 4096] bf16 (z at +2048)
    const float* __restrict__ A_log,   // [2048,16]
    const float* __restrict__ Dp,      // [2048]
    float* __restrict__ yg)            // [MR, 2048]  y * silu(z)  (== delta)
{
  __shared__ float s_ap[16][16];   // [seg][n]
  __shared__ float s_bc[16][16];
  __shared__ float s_h0[16][16];
  const int tid = threadIdx.x;
  const int n = tid & 15;
  const int seg = tid >> 4;
  const int chain = blockIdx.x;              // 0..4095
  const int b = chain >> 11;
  const int d = chain & (D_INNER - 1);
  const float a_c = -__expf(A_log[d * D_STATE + n]);
  const float Dv = Dp[d];
  const int row0 = b * SEQ + seg * 64;

  // Pass 1: per-segment affine composition.
  float aprod = 1.f, bacc = 0.f;
#pragma unroll 8
  for (int j = 0; j < 64; ++j) {
    const size_t row = row0 + j;
    float dv  = delta[row * D_INNER + d];
    float xcv = xc[row * D_INNER + d];
    float Bv  = xdbl[row * 96 + DT_RANK + n];
    float a   = __expf(dv * a_c);
    aprod *= a;
    bacc = a * bacc + dv * Bv * xcv;
  }
  s_ap[seg][n] = aprod;
  s_bc[seg][n] = bacc;
  __syncthreads();

  // Inter-segment exclusive scan (16 threads, one per n; 16 serial steps).
  if (tid < 16) {
    float h = 0.f;
#pragma unroll
    for (int s = 0; s < 16; ++s) {
      s_h0[s][tid] = h;
      h = s_ap[s][tid] * h + s_bc[s][tid];
    }
  }
  __syncthreads();

  // Pass 2: rescan with entry state; emit gated output.
  float h = s_h0[seg][n];
#pragma unroll 4
  for (int j = 0; j < 64; ++j) {
    const size_t row = row0 + j;
    float dv  = delta[row * D_INNER + d];
    float xcv = xc[row * D_INNER + d];
    float Bv  = xdbl[row * 96 + DT_RANK + n];
    float Cv  = xdbl[row * 96 + DT_RANK + D_STATE + n];
    float a   = __expf(dv * a_c);
    h = a * h + dv * Bv * xcv;
    float contrib = h * Cv;
#pragma unroll
    for (int off = 8; off; off >>= 1) contrib += __shfl_xor(contrib, off, 16);
    if (n == 0) {
      float zv = __bfloat162float(xz[row * (2 * D_INNER) + D_INNER + d]);
      float yv = contrib + xcv * Dv;
      yg[row * D_INNER + d] = yv * (zv / (1.f + __expf(-zv)));
    }
  }
}

extern "C" void kernel_launch(void* const* d_in, const int* in_sizes, int n_in,
                              void* d_out, int out_size, void* d_ws, size_t ws_size,
                              hipStream_t stream)
{
  // Reference dtypes: ALL inputs and the output are float32.
  const float* x     = (const float*)d_in[0];
  const float* W_in  = (const float*)d_in[1];
  const float* cw    = (const float*)d_in[2];
  const float* cb    = (const float*)d_in[3];
  const float* W_x   = (const float*)d_in[4];
  const float* W_dt  = (const float*)d_in[5];
  const float* b_dt  = (const float*)d_in[6];
  const float* A_log = (const float*)d_in[7];
  const float* Dp    = (const float*)d_in[8];
  const float* W_out = (const float*)d_in[9];
  float* out = (float*)d_out;

  // Workspace layout (51.2 MB total):
  //   xz   bf16 [MR,4096]  = 16.8 MB  (quantized intermediate; threshold is 2%)
  //   xc   f32  [MR,2048]  = 16.8 MB
  //   xdbl f32  [MR,  96]  =  0.8 MB
  //   delta f32 [MR,2048]  = 16.8 MB   (yg aliases delta — safe, see scan_kernel)
  char* wsb = (char*)d_ws;
  __hip_bfloat16* xz = (__hip_bfloat16*)wsb;
  float* xc    = (float*)(wsb + (size_t)MR * 4096 * 2);
  float* xdbl  = xc + (size_t)MR * 2048;
  float* delta = xdbl + (size_t)MR * 96;
  float* yg    = delta;   // in-place

  dim3 blk(256);

  // 1. xz = x @ W_in   (M=2048, N=4096, K=1024), bf16 store
  gemm_kernel<float, 2><<<dim3(4096 / 64, MR / 64), blk, 0, stream>>>(
      x, D_MODEL, W_in, 2 * D_INNER, nullptr, xz, 2 * D_INNER, MR, 2 * D_INNER, D_MODEL);

  // 2. conv + silu -> xc
  conv_silu_kernel<<<(MR * D_INNER) / 256, blk, 0, stream>>>(xz, cw, cb, xc);

  // 3. xdbl = xc @ W_x   (M=2048, N=96, K=2048)
  gemm_kernel<float, 0><<<dim3(2, MR / 64), blk, 0, stream>>>(
      xc, D_INNER, W_x, 96, nullptr, xdbl, 96, MR, 96, D_INNER);

  // 4. delta = softplus(xdbl[:, :64] @ W_dt + b_dt)   (M=2048, N=2048, K=64)
  gemm_kernel<float, 1><<<dim3(D_INNER / 64, MR / 64), blk, 0, stream>>>(
      xdbl, 96, W_dt, D_INNER, b_dt, delta, D_INNER, MR, D_INNER, DT_RANK);

  // 5. Chunked parallel SSM scan + D skip + silu(z) gating -> yg (in-place)
  scan_kernel<<<B_SZ * D_INNER, blk, 0, stream>>>(delta, xc, xdbl, xz, A_log, Dp, yg);

  // 6. out = yg @ W_out   (M=2048, N=1024, K=2048), fp32 store
  gemm_kernel<float, 0><<<dim3(D_MODEL / 64, MR / 64), blk, 0, stream>>>(
      yg, D_INNER, W_out, D_MODEL, nullptr, out, D_MODEL, MR, D_MODEL, D_INNER);
}

// Round 6
// 467.920 us; speedup vs baseline: 3.0821x; 2.0327x over previous
//
#include <hip/hip_runtime.h>
#include <hip/hip_bf16.h>

#define D_MODEL 1024
#define D_STATE 16
#define D_CONV  4
#define D_INNER 2048
#define DT_RANK 64
#define B_SZ 2
#define SEQ 1024
#define MR (B_SZ*SEQ)   // 2048 rows total

#define BM 128
#define BN 128
#define BK 64
#define LDK (BK + 8)   // LDS row pitch: +8 bf16 -> 16B-aligned rows

typedef float floatx4 __attribute__((ext_vector_type(4)));
typedef short short8 __attribute__((ext_vector_type(8)));

__device__ __forceinline__ float ldf(const __hip_bfloat16* p) { return __bfloat162float(*p); }

// ---------- prep: fp32 -> bf16 cast ----------
__global__ __launch_bounds__(256) void cast_kernel(
    const float* __restrict__ in, __hip_bfloat16* __restrict__ out, int n)
{
  int i = blockIdx.x * 256 + threadIdx.x;
  if (i < n) out[i] = __float2bfloat16(in[i]);
}

// ---------- prep: fp32 [R][C] -> bf16 [C][R] transpose ----------
__global__ __launch_bounds__(256) void transpose_cast_kernel(
    const float* __restrict__ in, __hip_bfloat16* __restrict__ out, int R, int C)
{
  __shared__ float t[32][33];
  const int x = threadIdx.x & 31;
  const int y4 = (threadIdx.x >> 5) * 4;
  const int bx = blockIdx.x * 32;   // along C
  const int by = blockIdx.y * 32;   // along R
#pragma unroll
  for (int i = 0; i < 4; ++i)
    t[y4 + i][x] = in[(size_t)(by + y4 + i) * C + bx + x];
  __syncthreads();
#pragma unroll
  for (int i = 0; i < 4; ++i)
    out[(size_t)(bx + y4 + i) * R + by + x] = __float2bfloat16(t[x][y4 + i]);
}

// ---------- MFMA GEMM: C[M,N] = A[M,K] * Bt[N,K]^T ----------
// A, Bt bf16, K-contiguous. Block tile 128x128, 4 waves (2x2), each wave
// 4x4 MFMA 16x16x32 tiles. Split-K via blockIdx.z (chunk Kc).
// EPI 0: f32 store; 1: softplus(acc+bias[n]) f32; 2: bf16 store;
// 3: f32 atomicAdd; 4: bf16 split store (col<D_INNER -> C, else -> C2).
template <int EPI>
__global__ __launch_bounds__(256) void mfma_gemm(
    const __hip_bfloat16* __restrict__ A, int lda,
    const __hip_bfloat16* __restrict__ Bt, int ldb,
    const float* __restrict__ bias,
    void* __restrict__ C, void* __restrict__ C2, int ldc,
    int M, int N, int Kc)
{
  __shared__ __hip_bfloat16 sA[BM][LDK];
  __shared__ __hip_bfloat16 sB[BN][LDK];
  const int tid = threadIdx.x;
  const int lane = tid & 63;
  const int wave = tid >> 6;
  const int wm = (wave & 1) * 64;
  const int wn = (wave >> 1) * 64;
  const int tm = lane & 15;
  const int quad = lane >> 4;
  const int m0 = blockIdx.y * BM;
  const int n0 = blockIdx.x * BN;
  const int kbeg = blockIdx.z * Kc;

  floatx4 acc[4][4];
#pragma unroll
  for (int i = 0; i < 4; ++i)
#pragma unroll
    for (int j = 0; j < 4; ++j) acc[i][j] = (floatx4){0.f, 0.f, 0.f, 0.f};

  for (int k0 = kbeg; k0 < kbeg + Kc; k0 += BK) {
#pragma unroll
    for (int i = 0; i < 4; ++i) {
      int q = tid + 256 * i;          // 0..1023
      int r = q >> 3;                 // 0..127
      int c = (q & 7) * 8;            // 0..56
      *(short8*)&sA[r][c] =
          *(const short8*)&A[(size_t)(m0 + r) * lda + k0 + c];
      int nr = n0 + r;
      if (nr < N) {
        *(short8*)&sB[r][c] =
            *(const short8*)&Bt[(size_t)nr * ldb + k0 + c];
      } else {
        *(short8*)&sB[r][c] = (short8){0,0,0,0,0,0,0,0};
      }
    }
    __syncthreads();
#pragma unroll
    for (int kk = 0; kk < BK; kk += 32) {
      short8 af[4], bfr[4];
#pragma unroll
      for (int i = 0; i < 4; ++i)
        af[i] = *(const short8*)&sA[wm + i * 16 + tm][kk + quad * 8];
#pragma unroll
      for (int j = 0; j < 4; ++j)
        bfr[j] = *(const short8*)&sB[wn + j * 16 + tm][kk + quad * 8];
#pragma unroll
      for (int i = 0; i < 4; ++i)
#pragma unroll
        for (int j = 0; j < 4; ++j)
          acc[i][j] = __builtin_amdgcn_mfma_f32_16x16x32_bf16(
              af[i], bfr[j], acc[i][j], 0, 0, 0);
    }
    __syncthreads();
  }

  // epilogue: C/D layout col=lane&15, row=quad*4+reg
#pragma unroll
  for (int i = 0; i < 4; ++i) {
#pragma unroll
    for (int j = 0; j < 4; ++j) {
      int col = n0 + wn + j * 16 + tm;
      if (col >= N) continue;
      int row = m0 + wm + i * 16 + quad * 4;
#pragma unroll
      for (int r = 0; r < 4; ++r) {
        float v = acc[i][j][r];
        size_t off = (size_t)(row + r) * ldc + col;
        if (EPI == 0) {
          ((float*)C)[off] = v;
        } else if (EPI == 1) {
          float xv = v + bias[col];
          ((float*)C)[off] = (xv > 15.f) ? xv : log1pf(__expf(xv));
        } else if (EPI == 2) {
          ((__hip_bfloat16*)C)[off] = __float2bfloat16(v);
        } else if (EPI == 3) {
          atomicAdd(&((float*)C)[off], v);
        } else {
          if (col < D_INNER)
            ((__hip_bfloat16*)C)[(size_t)(row + r) * D_INNER + col] = __float2bfloat16(v);
          else
            ((__hip_bfloat16*)C2)[(size_t)(row + r) * D_INNER + (col - D_INNER)] = __float2bfloat16(v);
        }
      }
    }
  }
}

// ---------- depthwise causal conv (4 taps) + bias + SiLU ----------
// reads xe (bf16 [MR, 2048]); writes xcb (bf16, [MR, 2048]).
__global__ __launch_bounds__(256) void conv_silu_kernel(
    const __hip_bfloat16* __restrict__ xe,
    const float* __restrict__ cw,
    const float* __restrict__ cb,
    __hip_bfloat16* __restrict__ xcb)
{
  int idx = blockIdx.x * 256 + threadIdx.x;     // over MR*D_INNER
  int c = idx & (D_INNER - 1);
  int row = idx >> 11;                          // b*SEQ + l
  int l = row & (SEQ - 1);
  int b = row >> 10;
  float acc = cb[c];
#pragma unroll
  for (int k = 0; k < D_CONV; ++k) {
    int ll = l - (D_CONV - 1) + k;
    if (ll >= 0)
      acc += ldf(&xe[((size_t)(b * SEQ + ll)) * D_INNER + c]) * cw[c * D_CONV + k];
  }
  xcb[idx] = __float2bfloat16(acc / (1.f + __expf(-acc)));   // silu
}

// ---------- chunked parallel SSM scan ----------
// One block per (b,d) chain; thread = (n = tid&15, seg = tid>>4).
__global__ __launch_bounds__(256) void scan_kernel(
    const float* __restrict__ delta,            // [MR, 2048] fp32
    const __hip_bfloat16* __restrict__ xcb,     // [MR, 2048] bf16
    const float* __restrict__ xdbl,             // [MR, 96]  (B at +64, C at +80)
    const __hip_bfloat16* __restrict__ z,       // [MR, 2048] bf16
    const float* __restrict__ A_log,            // [2048,16]
    const float* __restrict__ Dp,               // [2048]
    __hip_bfloat16* __restrict__ ygb)           // [MR, 2048] bf16  y * silu(z)
{
  __shared__ float s_ap[16][16];   // [seg][n]
  __shared__ float s_bc[16][16];
  __shared__ float s_h0[16][16];
  const int tid = threadIdx.x;
  const int n = tid & 15;
  const int seg = tid >> 4;
  const int chain = blockIdx.x;              // 0..4095
  const int b = chain >> 11;
  const int d = chain & (D_INNER - 1);
  const float a_c = -__expf(A_log[d * D_STATE + n]);
  const float Dv = Dp[d];
  const int row0 = b * SEQ + seg * 64;

  float aprod = 1.f, bacc = 0.f;
#pragma unroll 8
  for (int j = 0; j < 64; ++j) {
    const size_t row = row0 + j;
    float dv  = delta[row * D_INNER + d];
    float xcv = ldf(&xcb[row * D_INNER + d]);
    float Bv  = xdbl[row * 96 + DT_RANK + n];
    float a   = __expf(dv * a_c);
    aprod *= a;
    bacc = a * bacc + dv * Bv * xcv;
  }
  s_ap[seg][n] = aprod;
  s_bc[seg][n] = bacc;
  __syncthreads();

  if (tid < 16) {
    float h = 0.f;
#pragma unroll
    for (int s = 0; s < 16; ++s) {
      s_h0[s][tid] = h;
      h = s_ap[s][tid] * h + s_bc[s][tid];
    }
  }
  __syncthreads();

  float h = s_h0[seg][n];
#pragma unroll 4
  for (int j = 0; j < 64; ++j) {
    const size_t row = row0 + j;
    float dv  = delta[row * D_INNER + d];
    float xcv = ldf(&xcb[row * D_INNER + d]);
    float Bv  = xdbl[row * 96 + DT_RANK + n];
    float Cv  = xdbl[row * 96 + DT_RANK + D_STATE + n];
    float a   = __expf(dv * a_c);
    h = a * h + dv * Bv * xcv;
    float contrib = h * Cv;
#pragma unroll
    for (int off = 8; off; off >>= 1) contrib += __shfl_xor(contrib, off, 16);
    if (n == 0) {
      float zv = ldf(&z[row * D_INNER + d]);
      float yv = contrib + xcv * Dv;
      ygb[row * D_INNER + d] = __float2bfloat16(yv * (zv / (1.f + __expf(-zv))));
    }
  }
}

extern "C" void kernel_launch(void* const* d_in, const int* in_sizes, int n_in,
                              void* d_out, int out_size, void* d_ws, size_t ws_size,
                              hipStream_t stream)
{
  const float* x     = (const float*)d_in[0];
  const float* W_in  = (const float*)d_in[1];
  const float* cw    = (const float*)d_in[2];
  const float* cb    = (const float*)d_in[3];
  const float* W_x   = (const float*)d_in[4];
  const float* W_dt  = (const float*)d_in[5];
  const float* b_dt  = (const float*)d_in[6];
  const float* A_log = (const float*)d_in[7];
  const float* Dp    = (const float*)d_in[8];
  const float* W_out = (const float*)d_in[9];
  float* out = (float*)d_out;

  // Workspace layout: 45.375 MiB total (< 51.2 MB proven safe in R3/R4).
  // Lifetime-based overlays (stream-ordered, writer strictly after last reader):
  //   [ 0, 8)  WinT  (prep->G1)      overlaid by delta (written G4)
  //   [ 8,12)  xb    (prep->G1)      overlaid by delta
  //   [12,12.5) WxT  (prep->G3)      overlaid by delta
  //   [ 0,16)  delta (G4->scan)
  //   [16,24)  xe    (G1->conv)      overlaid by ygb (written scan)
  //   [24,32)  z     (G1->scan)
  //   [32,40)  xcb   (conv->scan)
  //   [40,44)  WoutT (prep->G6)
  //   [44,44.25) WdtT (prep->G4)
  //   [44.25,45) xdbl f32 (G3->scan)
  //   [45,45.375) xdblb (cast->G4)
  const size_t MiB = 1 << 20;
  char* wsb = (char*)d_ws;
  float*          delta = (float*)(wsb);
  __hip_bfloat16* WinT  = (__hip_bfloat16*)(wsb);
  __hip_bfloat16* xb    = (__hip_bfloat16*)(wsb + 8 * MiB);
  __hip_bfloat16* WxT   = (__hip_bfloat16*)(wsb + 12 * MiB);
  __hip_bfloat16* xe    = (__hip_bfloat16*)(wsb + 16 * MiB);
  __hip_bfloat16* ygb   = (__hip_bfloat16*)(wsb + 16 * MiB);
  __hip_bfloat16* z     = (__hip_bfloat16*)(wsb + 24 * MiB);
  __hip_bfloat16* xcb   = (__hip_bfloat16*)(wsb + 32 * MiB);
  __hip_bfloat16* WoutT = (__hip_bfloat16*)(wsb + 40 * MiB);
  __hip_bfloat16* WdtT  = (__hip_bfloat16*)(wsb + 44 * MiB);
  float*          xdbl  = (float*)(wsb + 44 * MiB + 256 * 1024);
  __hip_bfloat16* xdblb = (__hip_bfloat16*)(wsb + 45 * MiB);

  dim3 blk(256);

  // prep: casts + transposes (bf16, B^T K-contiguous layouts)
  cast_kernel<<<(MR * D_MODEL) / 256, blk, 0, stream>>>(x, xb, MR * D_MODEL);
  transpose_cast_kernel<<<dim3(4096 / 32, 1024 / 32), blk, 0, stream>>>(W_in, WinT, D_MODEL, 2 * D_INNER);
  transpose_cast_kernel<<<dim3(96 / 32, 2048 / 32), blk, 0, stream>>>(W_x, WxT, D_INNER, 96);
  transpose_cast_kernel<<<dim3(2048 / 32, 64 / 32), blk, 0, stream>>>(W_dt, WdtT, DT_RANK, D_INNER);
  transpose_cast_kernel<<<dim3(1024 / 32, 2048 / 32), blk, 0, stream>>>(W_out, WoutT, D_INNER, D_MODEL);

  // 1. [xe|z] = x @ W_in   (M=2048, N=4096, K=1024), bf16 split store
  mfma_gemm<4><<<dim3(4096 / BN, MR / BM, 1), blk, 0, stream>>>(
      xb, D_MODEL, WinT, D_MODEL, nullptr, xe, z, D_INNER, MR, 2 * D_INNER, D_MODEL);

  // 2. conv + silu -> xcb (bf16)
  conv_silu_kernel<<<(MR * D_INNER) / 256, blk, 0, stream>>>(xe, cw, cb, xcb);

  // 3. xdbl = xc @ W_x   (M=2048, N=96, K=2048), split-K=8 atomics
  hipMemsetAsync(xdbl, 0, (size_t)MR * 96 * 4, stream);
  mfma_gemm<3><<<dim3(1, MR / BM, 8), blk, 0, stream>>>(
      xcb, D_INNER, WxT, D_INNER, nullptr, xdbl, nullptr, 96, MR, 96, D_INNER / 8);
  cast_kernel<<<(MR * 96) / 256, blk, 0, stream>>>(xdbl, xdblb, MR * 96);

  // 4. delta = softplus(xdbl[:, :64] @ W_dt + b_dt)   (M=2048, N=2048, K=64)
  mfma_gemm<1><<<dim3(D_INNER / BN, MR / BM, 1), blk, 0, stream>>>(
      xdblb, 96, WdtT, DT_RANK, b_dt, delta, nullptr, D_INNER, MR, D_INNER, DT_RANK);

  // 5. chunked parallel SSM scan + D skip + silu(z) gating -> ygb (bf16)
  scan_kernel<<<B_SZ * D_INNER, blk, 0, stream>>>(delta, xcb, xdbl, z, A_log, Dp, ygb);

  // 6. out = yg @ W_out   (M=2048, N=1024, K=2048), split-K=2 atomics, fp32
  hipMemsetAsync(out, 0, (size_t)MR * D_MODEL * 4, stream);
  mfma_gemm<3><<<dim3(D_MODEL / BN, MR / BM, 2), blk, 0, stream>>>(
      ygb, D_INNER, WoutT, D_INNER, nullptr, out, nullptr, D_MODEL, MR, D_MODEL, D_INNER / 2);
}

// Round 7
// 388.919 us; speedup vs baseline: 3.7081x; 1.2031x over previous
//
#include <hip/hip_runtime.h>
#include <hip/hip_bf16.h>
#include <hip/hip_fp16.h>

#define D_MODEL 1024
#define D_STATE 16
#define D_CONV  4
#define D_INNER 2048
#define DT_RANK 64
#define B_SZ 2
#define SEQ 1024
#define MR (B_SZ*SEQ)   // 2048 rows total

#define BM 128
#define BN 128
#define BK 64
#define LDK (BK + 8)   // LDS row pitch: +8 bf16 -> 16B-aligned rows

typedef float floatx4 __attribute__((ext_vector_type(4)));
typedef short short8 __attribute__((ext_vector_type(8)));

__device__ __forceinline__ float ldf(const __hip_bfloat16* p) { return __bfloat162float(*p); }
__device__ __forceinline__ float ldf(const float* p) { return *p; }

// ---------- prep: fp32 -> bf16 cast ----------
__global__ __launch_bounds__(256) void cast_kernel(
    const float* __restrict__ in, __hip_bfloat16* __restrict__ out, int n)
{
  int i = blockIdx.x * 256 + threadIdx.x;
  if (i < n) out[i] = __float2bfloat16(in[i]);
}

// ---------- prep: [R][C] -> bf16 [C][R] transpose (IT = float or bf16) ----------
template <typename IT>
__global__ __launch_bounds__(256) void transpose_cast_kernel(
    const IT* __restrict__ in, __hip_bfloat16* __restrict__ out, int R, int C)
{
  __shared__ float t[32][33];
  const int x = threadIdx.x & 31;
  const int y4 = (threadIdx.x >> 5) * 4;
  const int bx = blockIdx.x * 32;   // along C
  const int by = blockIdx.y * 32;   // along R
#pragma unroll
  for (int i = 0; i < 4; ++i)
    t[y4 + i][x] = ldf(&in[(size_t)(by + y4 + i) * C + bx + x]);
  __syncthreads();
#pragma unroll
  for (int i = 0; i < 4; ++i)
    out[(size_t)(bx + y4 + i) * R + by + x] = __float2bfloat16(t[x][y4 + i]);
}

// ---------- MFMA GEMM: C[M,N] = A[M,K] * Bt[N,K]^T ----------
// EPI 0: f32 store; 2: bf16 store; 3: f32 atomicAdd;
// 4: bf16 split store (col<D_INNER -> C, else -> C2);
// 5: fp16 TRANSPOSED softplus store: Ct[col][row] = softplus(acc + bias[col]).
template <int EPI>
__global__ __launch_bounds__(256) void mfma_gemm(
    const __hip_bfloat16* __restrict__ A, int lda,
    const __hip_bfloat16* __restrict__ Bt, int ldb,
    const float* __restrict__ bias,
    void* __restrict__ C, void* __restrict__ C2, int ldc,
    int M, int N, int Kc)
{
  __shared__ __hip_bfloat16 sA[BM][LDK];
  __shared__ __hip_bfloat16 sB[BN][LDK];
  const int tid = threadIdx.x;
  const int lane = tid & 63;
  const int wave = tid >> 6;
  const int wm = (wave & 1) * 64;
  const int wn = (wave >> 1) * 64;
  const int tm = lane & 15;
  const int quad = lane >> 4;
  const int m0 = blockIdx.y * BM;
  const int n0 = blockIdx.x * BN;
  const int kbeg = blockIdx.z * Kc;

  floatx4 acc[4][4];
#pragma unroll
  for (int i = 0; i < 4; ++i)
#pragma unroll
    for (int j = 0; j < 4; ++j) acc[i][j] = (floatx4){0.f, 0.f, 0.f, 0.f};

  for (int k0 = kbeg; k0 < kbeg + Kc; k0 += BK) {
#pragma unroll
    for (int i = 0; i < 4; ++i) {
      int q = tid + 256 * i;          // 0..1023
      int r = q >> 3;                 // 0..127
      int c = (q & 7) * 8;            // 0..56
      *(short8*)&sA[r][c] =
          *(const short8*)&A[(size_t)(m0 + r) * lda + k0 + c];
      int nr = n0 + r;
      if (nr < N) {
        *(short8*)&sB[r][c] =
            *(const short8*)&Bt[(size_t)nr * ldb + k0 + c];
      } else {
        *(short8*)&sB[r][c] = (short8){0,0,0,0,0,0,0,0};
      }
    }
    __syncthreads();
#pragma unroll
    for (int kk = 0; kk < BK; kk += 32) {
      short8 af[4], bfr[4];
#pragma unroll
      for (int i = 0; i < 4; ++i)
        af[i] = *(const short8*)&sA[wm + i * 16 + tm][kk + quad * 8];
#pragma unroll
      for (int j = 0; j < 4; ++j)
        bfr[j] = *(const short8*)&sB[wn + j * 16 + tm][kk + quad * 8];
#pragma unroll
      for (int i = 0; i < 4; ++i)
#pragma unroll
        for (int j = 0; j < 4; ++j)
          acc[i][j] = __builtin_amdgcn_mfma_f32_16x16x32_bf16(
              af[i], bfr[j], acc[i][j], 0, 0, 0);
    }
    __syncthreads();
  }

  // epilogue: C/D layout col=lane&15, row=quad*4+reg
#pragma unroll
  for (int i = 0; i < 4; ++i) {
#pragma unroll
    for (int j = 0; j < 4; ++j) {
      int col = n0 + wn + j * 16 + tm;
      if (col >= N) continue;
      int row = m0 + wm + i * 16 + quad * 4;
#pragma unroll
      for (int r = 0; r < 4; ++r) {
        float v = acc[i][j][r];
        size_t off = (size_t)(row + r) * ldc + col;
        if (EPI == 0) {
          ((float*)C)[off] = v;
        } else if (EPI == 2) {
          ((__hip_bfloat16*)C)[off] = __float2bfloat16(v);
        } else if (EPI == 3) {
          atomicAdd(&((float*)C)[off], v);
        } else if (EPI == 4) {
          if (col < D_INNER)
            ((__hip_bfloat16*)C)[(size_t)(row + r) * D_INNER + col] = __float2bfloat16(v);
          else
            ((__hip_bfloat16*)C2)[(size_t)(row + r) * D_INNER + (col - D_INNER)] = __float2bfloat16(v);
        } else {  // EPI 5: transposed fp16 softplus
          float xv = v + bias[col];
          float sp = (xv > 15.f) ? xv : log1pf(__expf(xv));
          ((__half*)C)[(size_t)col * MR + (row + r)] = __float2half(sp);
        }
      }
    }
  }
}

// ---------- depthwise causal conv (4 taps) + bias + SiLU ----------
__global__ __launch_bounds__(256) void conv_silu_kernel(
    const __hip_bfloat16* __restrict__ xe,
    const float* __restrict__ cw,
    const float* __restrict__ cb,
    __hip_bfloat16* __restrict__ xcb)
{
  int idx = blockIdx.x * 256 + threadIdx.x;     // over MR*D_INNER
  int c = idx & (D_INNER - 1);
  int row = idx >> 11;                          // b*SEQ + l
  int l = row & (SEQ - 1);
  int b = row >> 10;
  float acc = cb[c];
#pragma unroll
  for (int k = 0; k < D_CONV; ++k) {
    int ll = l - (D_CONV - 1) + k;
    if (ll >= 0)
      acc += ldf(&xe[((size_t)(b * SEQ + ll)) * D_INNER + c]) * cw[c * D_CONV + k];
  }
  xcb[idx] = __float2bfloat16(acc / (1.f + __expf(-acc)));   // silu
}

// ---------- chunked parallel SSM scan, d-major streams ----------
// One block per (b,d) chain; thread = (n = tid&15, seg = tid>>4).
// Reads deltaT[d][row] fp16, xcT[d][row] bf16 (contiguous along l),
// B/C from xdbl (fp32, line-coalesced). Writes yT[d][row] = y + xc*D (pre-gate).
__global__ __launch_bounds__(256) void scan_kernel(
    const __half* __restrict__ deltaT,          // [D_INNER, MR]
    const __hip_bfloat16* __restrict__ xcT,     // [D_INNER, MR]
    const float* __restrict__ xdbl,             // [MR, 96]  (B at +64, C at +80)
    const float* __restrict__ A_log,            // [2048,16]
    const float* __restrict__ Dp,               // [2048]
    __hip_bfloat16* __restrict__ yT)            // [D_INNER, MR]
{
  __shared__ float s_ap[16][16];   // [seg][n]
  __shared__ float s_bc[16][16];
  __shared__ float s_h0[16][16];
  const int tid = threadIdx.x;
  const int n = tid & 15;
  const int seg = tid >> 4;
  const int chain = blockIdx.x;              // 0..4095
  const int b = chain >> 11;
  const int d = chain & (D_INNER - 1);
  const float a_c = -__expf(A_log[d * D_STATE + n]);
  const float Dv = Dp[d];
  const int rbase = b * SEQ + seg * 64;            // row index base
  const size_t cbase = (size_t)d * MR + rbase;     // d-major base

  float aprod = 1.f, bacc = 0.f;
#pragma unroll 8
  for (int j = 0; j < 64; ++j) {
    float dv  = __half2float(deltaT[cbase + j]);
    float xcv = ldf(&xcT[cbase + j]);
    float Bv  = xdbl[(size_t)(rbase + j) * 96 + DT_RANK + n];
    float a   = __expf(dv * a_c);
    aprod *= a;
    bacc = a * bacc + dv * Bv * xcv;
  }
  s_ap[seg][n] = aprod;
  s_bc[seg][n] = bacc;
  __syncthreads();

  if (tid < 16) {
    float h = 0.f;
#pragma unroll
    for (int s = 0; s < 16; ++s) {
      s_h0[s][tid] = h;
      h = s_ap[s][tid] * h + s_bc[s][tid];
    }
  }
  __syncthreads();

  float h = s_h0[seg][n];
#pragma unroll 4
  for (int j = 0; j < 64; ++j) {
    float dv  = __half2float(deltaT[cbase + j]);
    float xcv = ldf(&xcT[cbase + j]);
    float Bv  = xdbl[(size_t)(rbase + j) * 96 + DT_RANK + n];
    float Cv  = xdbl[(size_t)(rbase + j) * 96 + DT_RANK + D_STATE + n];
    float a   = __expf(dv * a_c);
    h = a * h + dv * Bv * xcv;
    float contrib = h * Cv;
#pragma unroll
    for (int off = 8; off; off >>= 1) contrib += __shfl_xor(contrib, off, 16);
    if (n == 0)
      yT[cbase + j] = __float2bfloat16(contrib + xcv * Dv);
  }
}

// ---------- gate: ygb[row][d] = yT[d][row] * silu(z[row][d]) (fused transpose) ----------
__global__ __launch_bounds__(256) void gate_kernel(
    const __hip_bfloat16* __restrict__ yT,   // [D_INNER, MR]
    const __hip_bfloat16* __restrict__ z,    // [MR, D_INNER]
    __hip_bfloat16* __restrict__ ygb)        // [MR, D_INNER]
{
  __shared__ float t[32][33];
  const int x = threadIdx.x & 31;
  const int y4 = (threadIdx.x >> 5) * 4;
  const int bx = blockIdx.x * 32;   // along MR
  const int by = blockIdx.y * 32;   // along D_INNER
#pragma unroll
  for (int i = 0; i < 4; ++i)
    t[y4 + i][x] = ldf(&yT[(size_t)(by + y4 + i) * MR + bx + x]);
  __syncthreads();
#pragma unroll
  for (int i = 0; i < 4; ++i) {
    int row = bx + y4 + i;
    int d = by + x;
    float zv = ldf(&z[(size_t)row * D_INNER + d]);
    float yv = t[x][y4 + i];
    ygb[(size_t)row * D_INNER + d] = __float2bfloat16(yv * (zv / (1.f + __expf(-zv))));
  }
}

extern "C" void kernel_launch(void* const* d_in, const int* in_sizes, int n_in,
                              void* d_out, int out_size, void* d_ws, size_t ws_size,
                              hipStream_t stream)
{
  const float* x     = (const float*)d_in[0];
  const float* W_in  = (const float*)d_in[1];
  const float* cw    = (const float*)d_in[2];
  const float* cb    = (const float*)d_in[3];
  const float* W_x   = (const float*)d_in[4];
  const float* W_dt  = (const float*)d_in[5];
  const float* b_dt  = (const float*)d_in[6];
  const float* A_log = (const float*)d_in[7];
  const float* Dp    = (const float*)d_in[8];
  const float* W_out = (const float*)d_in[9];
  float* out = (float*)d_out;

  // Workspace: 45.125 MiB total (≤ 45.375 proven). Lifetime overlays:
  //   [ 0, 8)  WinT (prep->G1)            -> xcT  (T-kernel->scan)
  //   [ 8,16)  xb[8,12) WxT[12,12.375) WdtT[12.375,12.625) -> yT (scan->gate)
  //   [16,24)  xe  (G1->conv)             -> ygb (gate->G6)
  //   [24,32)  z   (G1->gate)
  //   [32,40)  xcb (conv->{T,G3})         -> deltaT fp16 (G4->scan)
  //   [40,40.75)   xdbl f32 (G3->scan)
  //   [40.75,41.125) xdblb (cast->G4)
  //   [41.125,45.125) WoutT (prep->G6)
  const size_t MiB = 1 << 20;
  char* wsb = (char*)d_ws;
  __hip_bfloat16* WinT   = (__hip_bfloat16*)(wsb);
  __hip_bfloat16* xcT    = (__hip_bfloat16*)(wsb);
  __hip_bfloat16* xb     = (__hip_bfloat16*)(wsb + 8 * MiB);
  __hip_bfloat16* WxT    = (__hip_bfloat16*)(wsb + 12 * MiB);
  __hip_bfloat16* WdtT   = (__hip_bfloat16*)(wsb + 12 * MiB + 384 * 1024);
  __hip_bfloat16* yT     = (__hip_bfloat16*)(wsb + 8 * MiB);
  __hip_bfloat16* xe     = (__hip_bfloat16*)(wsb + 16 * MiB);
  __hip_bfloat16* ygb    = (__hip_bfloat16*)(wsb + 16 * MiB);
  __hip_bfloat16* z      = (__hip_bfloat16*)(wsb + 24 * MiB);
  __hip_bfloat16* xcb    = (__hip_bfloat16*)(wsb + 32 * MiB);
  __half*         deltaT = (__half*)(wsb + 32 * MiB);
  float*          xdbl   = (float*)(wsb + 40 * MiB);
  __hip_bfloat16* xdblb  = (__hip_bfloat16*)(wsb + 40 * MiB + 768 * 1024);
  __hip_bfloat16* WoutT  = (__hip_bfloat16*)(wsb + 41 * MiB + 128 * 1024);

  dim3 blk(256);

  // prep: casts + transposes (bf16, B^T K-contiguous layouts)
  cast_kernel<<<(MR * D_MODEL) / 256, blk, 0, stream>>>(x, xb, MR * D_MODEL);
  transpose_cast_kernel<float><<<dim3(4096 / 32, 1024 / 32), blk, 0, stream>>>(W_in, WinT, D_MODEL, 2 * D_INNER);
  transpose_cast_kernel<float><<<dim3(96 / 32, 2048 / 32), blk, 0, stream>>>(W_x, WxT, D_INNER, 96);
  transpose_cast_kernel<float><<<dim3(2048 / 32, 64 / 32), blk, 0, stream>>>(W_dt, WdtT, DT_RANK, D_INNER);
  transpose_cast_kernel<float><<<dim3(1024 / 32, 2048 / 32), blk, 0, stream>>>(W_out, WoutT, D_INNER, D_MODEL);

  // 1. [xe|z] = x @ W_in   (M=2048, N=4096, K=1024), bf16 split store
  mfma_gemm<4><<<dim3(4096 / BN, MR / BM, 1), blk, 0, stream>>>(
      xb, D_MODEL, WinT, D_MODEL, nullptr, xe, z, D_INNER, MR, 2 * D_INNER, D_MODEL);

  // 2. conv + silu -> xcb (bf16)
  conv_silu_kernel<<<(MR * D_INNER) / 256, blk, 0, stream>>>(xe, cw, cb, xcb);

  // 2b. xcT = xcb^T (d-major for the scan)
  transpose_cast_kernel<__hip_bfloat16><<<dim3(D_INNER / 32, MR / 32), blk, 0, stream>>>(
      xcb, xcT, MR, D_INNER);

  // 3. xdbl = xc @ W_x   (M=2048, N=96, K=2048), split-K=8 atomics
  hipMemsetAsync(xdbl, 0, (size_t)MR * 96 * 4, stream);
  mfma_gemm<3><<<dim3(1, MR / BM, 8), blk, 0, stream>>>(
      xcb, D_INNER, WxT, D_INNER, nullptr, xdbl, nullptr, 96, MR, 96, D_INNER / 8);
  cast_kernel<<<(MR * 96) / 256, blk, 0, stream>>>(xdbl, xdblb, MR * 96);

  // 4. deltaT = softplus(xdbl[:, :64] @ W_dt + b_dt)^T   (fp16, transposed store)
  mfma_gemm<5><<<dim3(D_INNER / BN, MR / BM, 1), blk, 0, stream>>>(
      xdblb, 96, WdtT, DT_RANK, b_dt, deltaT, nullptr, 0, MR, D_INNER, DT_RANK);

  // 5. chunked parallel SSM scan (d-major) + D skip -> yT (bf16, pre-gate)
  scan_kernel<<<B_SZ * D_INNER, blk, 0, stream>>>(deltaT, xcT, xdbl, A_log, Dp, yT);

  // 5b. gate: ygb = yT^T * silu(z)
  gate_kernel<<<dim3(MR / 32, D_INNER / 32), blk, 0, stream>>>(yT, z, ygb);

  // 6. out = yg @ W_out   (M=2048, N=1024, K=2048), split-K=2 atomics, fp32
  hipMemsetAsync(out, 0, (size_t)MR * D_MODEL * 4, stream);
  mfma_gemm<3><<<dim3(D_MODEL / BN, MR / BM, 2), blk, 0, stream>>>(
      ygb, D_INNER, WoutT, D_INNER, nullptr, out, nullptr, D_MODEL, MR, D_MODEL, D_INNER / 2);
}

// Round 8
// 343.943 us; speedup vs baseline: 4.1930x; 1.1308x over previous
//
#include <hip/hip_runtime.h>
#include <hip/hip_bf16.h>
#include <hip/hip_fp16.h>

#define D_MODEL 1024
#define D_STATE 16
#define D_CONV  4
#define D_INNER 2048
#define DT_RANK 64
#define B_SZ 2
#define SEQ 1024
#define MR (B_SZ*SEQ)   // 2048 rows total

#define BM 128
#define BN 128
#define BK 64
#define LDK (BK + 8)   // LDS row pitch: +8 bf16 -> 16B-aligned rows

typedef float floatx4 __attribute__((ext_vector_type(4)));
typedef short short8 __attribute__((ext_vector_type(8)));
typedef _Float16 half8 __attribute__((ext_vector_type(8)));

__device__ __forceinline__ float ldf(const __hip_bfloat16* p) { return __bfloat162float(*p); }
__device__ __forceinline__ float ldf(const float* p) { return *p; }
__device__ __forceinline__ float bf2f(short s) {
  union { unsigned u; float f; } v; v.u = ((unsigned)(unsigned short)s) << 16; return v.f;
}
__device__ __forceinline__ short f2bf(float f) {
  __hip_bfloat16 h = __float2bfloat16(f);
  return *reinterpret_cast<short*>(&h);
}

// ---------- prep: fp32 -> bf16 cast ----------
__global__ __launch_bounds__(256) void cast_kernel(
    const float* __restrict__ in, __hip_bfloat16* __restrict__ out, int n)
{
  int i = blockIdx.x * 256 + threadIdx.x;
  if (i < n) out[i] = __float2bfloat16(in[i]);
}

// ---------- prep: fp32 [R][C] -> bf16 [C][R] transpose ----------
__global__ __launch_bounds__(256) void transpose_cast_kernel(
    const float* __restrict__ in, __hip_bfloat16* __restrict__ out, int R, int C)
{
  __shared__ float t[32][33];
  const int x = threadIdx.x & 31;
  const int y4 = (threadIdx.x >> 5) * 4;
  const int bx = blockIdx.x * 32;   // along C
  const int by = blockIdx.y * 32;   // along R
#pragma unroll
  for (int i = 0; i < 4; ++i)
    t[y4 + i][x] = in[(size_t)(by + y4 + i) * C + bx + x];
  __syncthreads();
#pragma unroll
  for (int i = 0; i < 4; ++i)
    out[(size_t)(bx + y4 + i) * R + by + x] = __float2bfloat16(t[x][y4 + i]);
}

// ---------- MFMA GEMM: C[M,N] = A[M,K] * Bt[N,K]^T ----------
// EPI 0: f32 store; 2: bf16 store; 3: f32 atomicAdd;
// 4: bf16 split store (col<D_INNER -> C, else -> C2);
// 5: fp16 TRANSPOSED softplus store: Ct[col][row] = softplus(acc + bias[col]).
template <int EPI>
__global__ __launch_bounds__(256) void mfma_gemm(
    const __hip_bfloat16* __restrict__ A, int lda,
    const __hip_bfloat16* __restrict__ Bt, int ldb,
    const float* __restrict__ bias,
    void* __restrict__ C, void* __restrict__ C2, int ldc,
    int M, int N, int Kc)
{
  __shared__ __hip_bfloat16 sA[BM][LDK];
  __shared__ __hip_bfloat16 sB[BN][LDK];
  const int tid = threadIdx.x;
  const int lane = tid & 63;
  const int wave = tid >> 6;
  const int wm = (wave & 1) * 64;
  const int wn = (wave >> 1) * 64;
  const int tm = lane & 15;
  const int quad = lane >> 4;
  const int m0 = blockIdx.y * BM;
  const int n0 = blockIdx.x * BN;
  const int kbeg = blockIdx.z * Kc;

  floatx4 acc[4][4];
#pragma unroll
  for (int i = 0; i < 4; ++i)
#pragma unroll
    for (int j = 0; j < 4; ++j) acc[i][j] = (floatx4){0.f, 0.f, 0.f, 0.f};

  for (int k0 = kbeg; k0 < kbeg + Kc; k0 += BK) {
#pragma unroll
    for (int i = 0; i < 4; ++i) {
      int q = tid + 256 * i;          // 0..1023
      int r = q >> 3;                 // 0..127
      int c = (q & 7) * 8;            // 0..56
      *(short8*)&sA[r][c] =
          *(const short8*)&A[(size_t)(m0 + r) * lda + k0 + c];
      int nr = n0 + r;
      if (nr < N) {
        *(short8*)&sB[r][c] =
            *(const short8*)&Bt[(size_t)nr * ldb + k0 + c];
      } else {
        *(short8*)&sB[r][c] = (short8){0,0,0,0,0,0,0,0};
      }
    }
    __syncthreads();
#pragma unroll
    for (int kk = 0; kk < BK; kk += 32) {
      short8 af[4], bfr[4];
#pragma unroll
      for (int i = 0; i < 4; ++i)
        af[i] = *(const short8*)&sA[wm + i * 16 + tm][kk + quad * 8];
#pragma unroll
      for (int j = 0; j < 4; ++j)
        bfr[j] = *(const short8*)&sB[wn + j * 16 + tm][kk + quad * 8];
#pragma unroll
      for (int i = 0; i < 4; ++i)
#pragma unroll
        for (int j = 0; j < 4; ++j)
          acc[i][j] = __builtin_amdgcn_mfma_f32_16x16x32_bf16(
              af[i], bfr[j], acc[i][j], 0, 0, 0);
    }
    __syncthreads();
  }

  // epilogue: C/D layout col=lane&15, row=quad*4+reg
#pragma unroll
  for (int i = 0; i < 4; ++i) {
#pragma unroll
    for (int j = 0; j < 4; ++j) {
      int col = n0 + wn + j * 16 + tm;
      if (col >= N) continue;
      int row = m0 + wm + i * 16 + quad * 4;
#pragma unroll
      for (int r = 0; r < 4; ++r) {
        float v = acc[i][j][r];
        size_t off = (size_t)(row + r) * ldc + col;
        if (EPI == 0) {
          ((float*)C)[off] = v;
        } else if (EPI == 2) {
          ((__hip_bfloat16*)C)[off] = __float2bfloat16(v);
        } else if (EPI == 3) {
          atomicAdd(&((float*)C)[off], v);
        } else if (EPI == 4) {
          if (col < D_INNER)
            ((__hip_bfloat16*)C)[(size_t)(row + r) * D_INNER + col] = __float2bfloat16(v);
          else
            ((__hip_bfloat16*)C2)[(size_t)(row + r) * D_INNER + (col - D_INNER)] = __float2bfloat16(v);
        } else {  // EPI 5: transposed fp16 softplus
          float xv = v + bias[col];
          float sp = (xv > 15.f) ? xv : log1pf(__expf(xv));
          ((__half*)C)[(size_t)col * MR + (row + r)] = __float2half(sp);
        }
      }
    }
  }
}

// ---------- depthwise causal conv (4 taps) + bias + SiLU, dual-layout output ----------
// Tiled: 32 rows x 32 channels per block; writes xcb[row][c] and xcT[c][row].
__global__ __launch_bounds__(256) void conv_silu_T_kernel(
    const __hip_bfloat16* __restrict__ xe,    // [MR, D_INNER]
    const float* __restrict__ cw,
    const float* __restrict__ cb,
    __hip_bfloat16* __restrict__ xcb,         // [MR, D_INNER]
    __hip_bfloat16* __restrict__ xcT)         // [D_INNER, MR]
{
  __shared__ float t[32][33];    // [c in tile][row in tile]
  const int x = threadIdx.x & 31;          // channel within tile
  const int y4 = (threadIdx.x >> 5) * 4;   // row group
  const int row0 = blockIdx.x * 32;        // along MR (tiles never cross batch: 32 | 1024)
  const int c0 = blockIdx.y * 32;          // along D_INNER
  const int c = c0 + x;
  const float w0 = cw[c * D_CONV + 0], w1 = cw[c * D_CONV + 1],
              w2 = cw[c * D_CONV + 2], w3 = cw[c * D_CONV + 3];
  const float bias = cb[c];
#pragma unroll
  for (int i = 0; i < 4; ++i) {
    int row = row0 + y4 + i;
    int l = row & (SEQ - 1);
    float acc = bias;
    const __hip_bfloat16* p = &xe[(size_t)row * D_INNER + c];
    acc += ldf(p) * w3;
    if (l >= 1) acc += ldf(p - D_INNER) * w2;
    if (l >= 2) acc += ldf(p - 2 * D_INNER) * w1;
    if (l >= 3) acc += ldf(p - 3 * D_INNER) * w0;
    float s = acc / (1.f + __expf(-acc));
    xcb[(size_t)row * D_INNER + c] = __float2bfloat16(s);
    t[x][y4 + i] = s;
  }
  __syncthreads();
#pragma unroll
  for (int i = 0; i < 4; ++i)
    xcT[(size_t)(c0 + y4 + i) * MR + row0 + x] = __float2bfloat16(t[y4 + i][x]);
}

// ---------- chunked parallel SSM scan, d-major vectorized streams ----------
// One block per (b,d) chain; thread = (n = tid&15, seg = tid>>4).
__global__ __launch_bounds__(256) void scan_kernel(
    const __half* __restrict__ deltaT,          // [D_INNER, MR]
    const __hip_bfloat16* __restrict__ xcT,     // [D_INNER, MR]
    const float* __restrict__ xdbl,             // [MR, 96]  (B at +64, C at +80)
    const float* __restrict__ A_log,            // [2048,16]
    const float* __restrict__ Dp,               // [2048]
    __hip_bfloat16* __restrict__ yT)            // [D_INNER, MR]
{
  __shared__ float s_ap[16][16];   // [seg][n]
  __shared__ float s_bc[16][16];
  __shared__ float s_h0[16][16];
  const int tid = threadIdx.x;
  const int n = tid & 15;
  const int seg = tid >> 4;
  const int chain = blockIdx.x;              // 0..4095
  const int b = chain >> 11;
  const int d = chain & (D_INNER - 1);
  const float a_c = -__expf(A_log[d * D_STATE + n]);
  const float Dv = Dp[d];
  const int rbase = b * SEQ + seg * 64;            // row index base
  const size_t cbase = (size_t)d * MR + rbase;     // d-major base (16B aligned)

  // Pass 1: per-segment affine composition (vectorized 16B loads, 8 steps each).
  float aprod = 1.f, bacc = 0.f;
  for (int c8 = 0; c8 < 8; ++c8) {
    half8 dv8 = *(const half8*)&deltaT[cbase + c8 * 8];
    short8 xc8 = *(const short8*)&xcT[cbase + c8 * 8];
#pragma unroll
    for (int j = 0; j < 8; ++j) {
      float dv  = (float)dv8[j];
      float xcv = bf2f(xc8[j]);
      float Bv  = xdbl[(size_t)(rbase + c8 * 8 + j) * 96 + DT_RANK + n];
      float a   = __expf(dv * a_c);
      aprod *= a;
      bacc = a * bacc + dv * Bv * xcv;
    }
  }
  s_ap[seg][n] = aprod;
  s_bc[seg][n] = bacc;
  __syncthreads();

  // Inter-segment exclusive scan (16 threads, one per n).
  if (tid < 16) {
    float h = 0.f;
#pragma unroll
    for (int s = 0; s < 16; ++s) {
      s_h0[s][tid] = h;
      h = s_ap[s][tid] * h + s_bc[s][tid];
    }
  }
  __syncthreads();

  // Pass 2: rescan with entry state; reduce over n; buffered 16B stores.
  float h = s_h0[seg][n];
  for (int c8 = 0; c8 < 8; ++c8) {
    half8 dv8 = *(const half8*)&deltaT[cbase + c8 * 8];
    short8 xc8 = *(const short8*)&xcT[cbase + c8 * 8];
    short8 ybuf;
#pragma unroll
    for (int j = 0; j < 8; ++j) {
      float dv  = (float)dv8[j];
      float xcv = bf2f(xc8[j]);
      size_t rr = (size_t)(rbase + c8 * 8 + j) * 96;
      float Bv  = xdbl[rr + DT_RANK + n];
      float Cv  = xdbl[rr + DT_RANK + D_STATE + n];
      float a   = __expf(dv * a_c);
      h = a * h + dv * Bv * xcv;
      float contrib = h * Cv;
#pragma unroll
      for (int off = 8; off; off >>= 1) contrib += __shfl_xor(contrib, off, 16);
      ybuf[j] = f2bf(contrib + xcv * Dv);
    }
    if (n == 0)
      *(short8*)&yT[cbase + c8 * 8] = ybuf;
  }
}

// ---------- gate: ygb[row][d] = yT[d][row] * silu(z[row][d]) (fused transpose) ----------
__global__ __launch_bounds__(256) void gate_kernel(
    const __hip_bfloat16* __restrict__ yT,   // [D_INNER, MR]
    const __hip_bfloat16* __restrict__ z,    // [MR, D_INNER]
    __hip_bfloat16* __restrict__ ygb)        // [MR, D_INNER]
{
  __shared__ float t[32][33];
  const int x = threadIdx.x & 31;
  const int y4 = (threadIdx.x >> 5) * 4;
  const int bx = blockIdx.x * 32;   // along MR
  const int by = blockIdx.y * 32;   // along D_INNER
#pragma unroll
  for (int i = 0; i < 4; ++i)
    t[y4 + i][x] = ldf(&yT[(size_t)(by + y4 + i) * MR + bx + x]);
  __syncthreads();
#pragma unroll
  for (int i = 0; i < 4; ++i) {
    int row = bx + y4 + i;
    int d = by + x;
    float zv = ldf(&z[(size_t)row * D_INNER + d]);
    float yv = t[x][y4 + i];
    ygb[(size_t)row * D_INNER + d] = __float2bfloat16(yv * (zv / (1.f + __expf(-zv))));
  }
}

extern "C" void kernel_launch(void* const* d_in, const int* in_sizes, int n_in,
                              void* d_out, int out_size, void* d_ws, size_t ws_size,
                              hipStream_t stream)
{
  const float* x     = (const float*)d_in[0];
  const float* W_in  = (const float*)d_in[1];
  const float* cw    = (const float*)d_in[2];
  const float* cb    = (const float*)d_in[3];
  const float* W_x   = (const float*)d_in[4];
  const float* W_dt  = (const float*)d_in[5];
  const float* b_dt  = (const float*)d_in[6];
  const float* A_log = (const float*)d_in[7];
  const float* Dp    = (const float*)d_in[8];
  const float* W_out = (const float*)d_in[9];
  float* out = (float*)d_out;

  // Workspace: 45.125 MiB total. Lifetime overlays (stream-ordered):
  //   [ 0, 8)  WinT (prep->G1)            -> xcT  (conv->scan)
  //   [ 8,16)  xb[8,12) WxT[12,12.375) WdtT[12.375,12.625) -> yT (scan->gate)
  //   [16,24)  xe  (G1->conv)             -> ygb (gate->G6)
  //   [24,32)  z   (G1->gate)
  //   [32,40)  xcb (conv->G3)             -> deltaT fp16 (G4->scan)
  //   [40,40.75)   xdbl f32 (G3->scan)
  //   [40.75,41.125) xdblb (cast->G4)
  //   [41.125,45.125) WoutT (prep->G6)
  const size_t MiB = 1 << 20;
  char* wsb = (char*)d_ws;
  __hip_bfloat16* WinT   = (__hip_bfloat16*)(wsb);
  __hip_bfloat16* xcT    = (__hip_bfloat16*)(wsb);
  __hip_bfloat16* xb     = (__hip_bfloat16*)(wsb + 8 * MiB);
  __hip_bfloat16* WxT    = (__hip_bfloat16*)(wsb + 12 * MiB);
  __hip_bfloat16* WdtT   = (__hip_bfloat16*)(wsb + 12 * MiB + 384 * 1024);
  __hip_bfloat16* yT     = (__hip_bfloat16*)(wsb + 8 * MiB);
  __hip_bfloat16* xe     = (__hip_bfloat16*)(wsb + 16 * MiB);
  __hip_bfloat16* ygb    = (__hip_bfloat16*)(wsb + 16 * MiB);
  __hip_bfloat16* z      = (__hip_bfloat16*)(wsb + 24 * MiB);
  __hip_bfloat16* xcb    = (__hip_bfloat16*)(wsb + 32 * MiB);
  __half*         deltaT = (__half*)(wsb + 32 * MiB);
  float*          xdbl   = (float*)(wsb + 40 * MiB);
  __hip_bfloat16* xdblb  = (__hip_bfloat16*)(wsb + 40 * MiB + 768 * 1024);
  __hip_bfloat16* WoutT  = (__hip_bfloat16*)(wsb + 41 * MiB + 128 * 1024);

  dim3 blk(256);

  // prep: casts + transposes (bf16, B^T K-contiguous layouts)
  cast_kernel<<<(MR * D_MODEL) / 256, blk, 0, stream>>>(x, xb, MR * D_MODEL);
  transpose_cast_kernel<<<dim3(4096 / 32, 1024 / 32), blk, 0, stream>>>(W_in, WinT, D_MODEL, 2 * D_INNER);
  transpose_cast_kernel<<<dim3(96 / 32, 2048 / 32), blk, 0, stream>>>(W_x, WxT, D_INNER, 96);
  transpose_cast_kernel<<<dim3(2048 / 32, 64 / 32), blk, 0, stream>>>(W_dt, WdtT, DT_RANK, D_INNER);
  transpose_cast_kernel<<<dim3(1024 / 32, 2048 / 32), blk, 0, stream>>>(W_out, WoutT, D_INNER, D_MODEL);

  // 1. [xe|z] = x @ W_in   (M=2048, N=4096, K=1024), bf16 split store
  mfma_gemm<4><<<dim3(4096 / BN, MR / BM, 1), blk, 0, stream>>>(
      xb, D_MODEL, WinT, D_MODEL, nullptr, xe, z, D_INNER, MR, 2 * D_INNER, D_MODEL);

  // 2. conv + silu -> xcb (row-major) AND xcT (d-major), one pass
  conv_silu_T_kernel<<<dim3(MR / 32, D_INNER / 32), blk, 0, stream>>>(xe, cw, cb, xcb, xcT);

  // 3. xdbl = xc @ W_x   (M=2048, N=96, K=2048), split-K=8 atomics
  hipMemsetAsync(xdbl, 0, (size_t)MR * 96 * 4, stream);
  mfma_gemm<3><<<dim3(1, MR / BM, 8), blk, 0, stream>>>(
      xcb, D_INNER, WxT, D_INNER, nullptr, xdbl, nullptr, 96, MR, 96, D_INNER / 8);
  cast_kernel<<<(MR * 96) / 256, blk, 0, stream>>>(xdbl, xdblb, MR * 96);

  // 4. deltaT = softplus(xdbl[:, :64] @ W_dt + b_dt)^T   (fp16, transposed store)
  mfma_gemm<5><<<dim3(D_INNER / BN, MR / BM, 1), blk, 0, stream>>>(
      xdblb, 96, WdtT, DT_RANK, b_dt, deltaT, nullptr, 0, MR, D_INNER, DT_RANK);

  // 5. chunked parallel SSM scan (d-major, vectorized) + D skip -> yT
  scan_kernel<<<B_SZ * D_INNER, blk, 0, stream>>>(deltaT, xcT, xdbl, A_log, Dp, yT);

  // 5b. gate: ygb = yT^T * silu(z)
  gate_kernel<<<dim3(MR / 32, D_INNER / 32), blk, 0, stream>>>(yT, z, ygb);

  // 6. out = yg @ W_out   (M=2048, N=1024, K=2048), split-K=2 atomics, fp32
  hipMemsetAsync(out, 0, (size_t)MR * D_MODEL * 4, stream);
  mfma_gemm<3><<<dim3(D_MODEL / BN, MR / BM, 2), blk, 0, stream>>>(
      ygb, D_INNER, WoutT, D_INNER, nullptr, out, nullptr, D_MODEL, MR, D_MODEL, D_INNER / 2);
}